// Round 1
// baseline (555.249 us; speedup 1.0000x reference)
//
#include <hip/hip_runtime.h>
#include <math.h>

#define KK3 3
#define CIN 66
#define UPC 64
#define BN_EPS 1e-5f

#define B 8
#define H 128
#define W 128
#define C1 64
#define C2 128
#define KSQ 256

// ---- ws layout (float offsets) ----
#define UP_OFF   0
#define UP_SIZE  (B*UPC*H*W)            // 8*64*128*128 = 8388608
#define WCT_OFF  (UP_OFF + UP_SIZE)     // wc_t [66][9][64]
#define WCT_SIZE (CIN*9*64)             // 38016
#define WSQT_OFF (WCT_OFF + WCT_SIZE)   // wsq_t [256][128]
#define WSQT_SIZE (KSQ*C2)              // 32768
#define SC_OFF   (WSQT_OFF + WSQT_SIZE) // scale [594]
#define SH_OFF   (SC_OFF + CIN*9)       // shift [594]

// ------------------------------------------------------------------
// Kernel 0: weight transposes + BN fold
// ------------------------------------------------------------------
__global__ void prep_kernel(const float* __restrict__ w_squeeze,
                            const float* __restrict__ w_conv,
                            const float* __restrict__ gamma,
                            const float* __restrict__ beta,
                            const float* __restrict__ mean,
                            const float* __restrict__ var,
                            float* __restrict__ ws)
{
    int tid = blockIdx.x * blockDim.x + threadIdx.x;
    int nth = gridDim.x * blockDim.x;
    // w_conv [64][66*9] -> wc_t [66*9][64]
    for (int i = tid; i < 64 * CIN * 9; i += nth) {
        int o = i / (CIN * 9);
        int cj = i % (CIN * 9);
        ws[WCT_OFF + cj * 64 + o] = w_conv[i];
    }
    // w_squeeze [128][256] -> wsq_t [256][128]
    for (int i = tid; i < C2 * KSQ; i += nth) {
        int o = i / KSQ, k = i % KSQ;
        ws[WSQT_OFF + k * C2 + o] = w_squeeze[i];
    }
    // BN fold
    for (int i = tid; i < CIN * 9; i += nth) {
        float sc = gamma[i] / sqrtf(var[i] + BN_EPS);
        ws[SC_OFF + i] = sc;
        ws[SH_OFF + i] = beta[i] - mean[i] * sc;
    }
}

// ------------------------------------------------------------------
// Kernel 1: space-to-depth + 1x1 squeeze conv (fp32 GEMM)
//   M = 8*128*128 locations, K = 256, N = 128
//   block: 256 threads, tile 64 locations x 128 outputs
//   writes up channels (0..63) to ws, low channels to d_out (permuted)
// ------------------------------------------------------------------
__global__ __launch_bounds__(256) void squeeze_kernel(
    const float* __restrict__ x,
    float* __restrict__ wsp,
    float* __restrict__ out)
{
    __shared__ __align__(16) float As[32][64];
    __shared__ __align__(16) float Bs[32][C2];

    const int m0 = blockIdx.x * 64;
    const int w0 = m0 & 127;          // 0 or 64
    const int h  = (m0 >> 7) & 127;
    const int b  = m0 >> 14;
    const int tid = threadIdx.x;
    const int lg = tid & 15;          // location group: 4 consecutive w
    const int og = tid >> 4;          // output group: 8 consecutive o

    const float* wsq_t = wsp + WSQT_OFF;

    float acc[4][8];
#pragma unroll
    for (int i = 0; i < 4; ++i)
#pragma unroll
        for (int oo = 0; oo < 8; ++oo) acc[i][oo] = 0.f;

#pragma unroll 1
    for (int q = 0; q < 8; ++q) {
        const int rg = q & 1;            // input row parity
        const int c0 = (q >> 1) * 16;    // channel base (16 channels/chunk)
        __syncthreads();
        // stage A: chunk k = {cg,cc}: k_local = cc*2+cg; 16cc x 64t float2 loads
#pragma unroll
        for (int it = 0; it < 4; ++it) {
            int idx = tid + it * 256;
            int cc = idx >> 6;
            int t  = idx & 63;
            int c  = c0 + cc;
            const float2 v = *(const float2*)(x +
                ((((size_t)b * C1 + c) * 256 + (2 * h + rg)) * 256 + 2 * (w0 + t)));
            As[cc * 2 + 0][t] = v.x;   // cg=0 -> g=rg
            As[cc * 2 + 1][t] = v.y;   // cg=1 -> g=rg+2
        }
        // stage B: 32 rows x 128 outs, float4
#pragma unroll
        for (int it = 0; it < 4; ++it) {
            int idx = tid + it * 256;
            int kk = idx >> 5;
            int o4 = (idx & 31) * 4;
            int cc = kk >> 1, cg = kk & 1;
            int kglob = (cg ? (rg + 2) : rg) * 64 + c0 + cc;
            *(float4*)&Bs[kk][o4] = *(const float4*)(wsq_t + kglob * C2 + o4);
        }
        __syncthreads();
#pragma unroll
        for (int kk = 0; kk < 32; ++kk) {
            const float4 a  = *(const float4*)&As[kk][lg * 4];
            const float4 u0 = *(const float4*)&Bs[kk][og * 8];
            const float4 u1 = *(const float4*)&Bs[kk][og * 8 + 4];
            const float av[4] = {a.x, a.y, a.z, a.w};
            const float wv[8] = {u0.x, u0.y, u0.z, u0.w, u1.x, u1.y, u1.z, u1.w};
#pragma unroll
            for (int i = 0; i < 4; ++i)
#pragma unroll
                for (int oo = 0; oo < 8; ++oo)
                    acc[i][oo] = fmaf(av[i], wv[oo], acc[i][oo]);
        }
    }

    const int wcol = w0 + lg * 4;
#pragma unroll
    for (int oo = 0; oo < 8; ++oo) {
        const int oc = og * 8 + oo;
        float4 v = {acc[0][oo], acc[1][oo], acc[2][oo], acc[3][oo]};
        if (oc < UPC) {
            *(float4*)(wsp + UP_OFF + (((size_t)b * UPC + oc) * H + h) * W + wcol) = v;
        } else {
            const int lc = oc - UPC;
            const int ch = (lc & 1) ? (96 + ((lc - 1) >> 1)) : (32 + (lc >> 1));
            *(float4*)(out + (((size_t)b * C2 + ch) * H + h) * W + wcol) = v;
        }
    }
}

// ------------------------------------------------------------------
// Kernel 2: fused avgpool/softmax-weight/feat-conv/BN/ReLU/CARAFE-matvec
//   one thread per output pixel, 16x16 tile per block, 6-channel LDS chunks
// ------------------------------------------------------------------
__global__ __launch_bounds__(256) void fused_kernel(
    const float* __restrict__ wsp,
    const float* __restrict__ w_gw,
    const float* __restrict__ w_gf,
    const float* __restrict__ b_conv,
    float* __restrict__ out)
{
    __shared__ float sgw[CIN * 9];
    __shared__ float sgf[CIN * 9 * 9];
    __shared__ float ssc[CIN * 9];
    __shared__ float ssh[CIN * 9];
    __shared__ float tile[6][18][19];

    const int bx = blockIdx.x;
    const int w0 = (bx & 7) * 16;
    const int h0 = ((bx >> 3) & 7) * 16;
    const int b  = bx >> 6;
    const int tid = threadIdx.x;
    const int tx = tid & 15, ty = tid >> 4;
    const int h = h0 + ty, w = w0 + tx;

    for (int i = tid; i < CIN * 9; i += 256) {
        sgw[i] = w_gw[i];
        ssc[i] = wsp[SC_OFF + i];
        ssh[i] = wsp[SH_OFF + i];
    }
    for (int i = tid; i < CIN * 81; i += 256) sgf[i] = w_gf[i];

    float acc[64];
#pragma unroll
    for (int o = 0; o < 64; ++o) acc[o] = b_conv[o];

    const float* upg = wsp + UP_OFF + (size_t)b * UPC * H * W;
    const float* wct = wsp + WCT_OFF;

#pragma unroll 1
    for (int cc = 0; cc < CIN; cc += 6) {
        __syncthreads();
        for (int idx = tid; idx < 6 * 18 * 18; idx += 256) {
            int l  = idx / 324;
            int r  = idx - l * 324;
            int yy = r / 18, xx = r - yy * 18;
            int gy = h0 - 1 + yy, gx = w0 - 1 + xx;
            int c  = cc + l;
            float v = 0.f;
            if (gy >= 0 && gy < H && gx >= 0 && gx < W) {
                if (c < UPC)      v = upg[((size_t)c * H + gy) * W + gx];
                else if (c == 64) v = gx * (2.f / 127.f) - 1.f;
                else              v = gy * (2.f / 127.f) - 1.f;
            }
            tile[l][yy][xx] = v;
        }
        __syncthreads();
#pragma unroll 1
        for (int l = 0; l < 6; ++l) {
            const int c = cc + l;
            float n[9];
#pragma unroll
            for (int dy = 0; dy < 3; ++dy)
#pragma unroll
                for (int dx = 0; dx < 3; ++dx)
                    n[dy * 3 + dx] = tile[l][ty + dy][tx + dx];
            const float p = (n[0] + n[1] + n[2] + n[3] + n[4] + n[5] + n[6] + n[7] + n[8]) * (1.f / 9.f);

            float lo[9], m = -INFINITY;
#pragma unroll
            for (int j = 0; j < 9; ++j) { lo[j] = p * sgw[c * 9 + j]; m = fmaxf(m, lo[j]); }
            float e[9], se = 0.f;
#pragma unroll
            for (int j = 0; j < 9; ++j) { e[j] = __expf(lo[j] - m); se += e[j]; }
            const float sinv = 1.f / se;

            float fs[9];
#pragma unroll
            for (int j = 0; j < 9; ++j) {
                const float* gf = &sgf[(c * 9 + j) * 9];
                float cv = n[0] * gf[0];
                cv = fmaf(n[1], gf[1], cv); cv = fmaf(n[2], gf[2], cv);
                cv = fmaf(n[3], gf[3], cv); cv = fmaf(n[4], gf[4], cv);
                cv = fmaf(n[5], gf[5], cv); cv = fmaf(n[6], gf[6], cv);
                cv = fmaf(n[7], gf[7], cv); cv = fmaf(n[8], gf[8], cv);
                float f = fmaf(cv, ssc[c * 9 + j], ssh[c * 9 + j]);
                f = fmaxf(f, 0.f);
                fs[j] = f * (e[j] * sinv);
            }

            const float* wrow = wct + c * 576;   // [j][64], wave-uniform address
#pragma unroll
            for (int j = 0; j < 9; ++j) {
                const float fsj = fs[j];
                const float* wr = wrow + j * 64;
#pragma unroll
                for (int o4 = 0; o4 < 64; o4 += 4) {
                    const float4 wv = *(const float4*)(wr + o4);
                    acc[o4 + 0] = fmaf(fsj, wv.x, acc[o4 + 0]);
                    acc[o4 + 1] = fmaf(fsj, wv.y, acc[o4 + 1]);
                    acc[o4 + 2] = fmaf(fsj, wv.z, acc[o4 + 2]);
                    acc[o4 + 3] = fmaf(fsj, wv.w, acc[o4 + 3]);
                }
            }
        }
    }

    // final output: y channel oc -> out channel (even: oc/2, odd: 64+oc/2)
#pragma unroll
    for (int oc = 0; oc < 64; ++oc) {
        const int ch = (oc & 1) ? (64 + (oc >> 1)) : (oc >> 1);
        out[(((size_t)b * C2 + ch) * H + h) * W + w] = acc[oc];
    }
}

// ------------------------------------------------------------------
extern "C" void kernel_launch(void* const* d_in, const int* in_sizes, int n_in,
                              void* d_out, int out_size, void* d_ws, size_t ws_size,
                              hipStream_t stream)
{
    const float* x         = (const float*)d_in[0];
    const float* w_squeeze = (const float*)d_in[1];
    const float* w_gw      = (const float*)d_in[2];
    const float* w_gf      = (const float*)d_in[3];
    const float* gamma     = (const float*)d_in[4];
    const float* beta      = (const float*)d_in[5];
    const float* mean      = (const float*)d_in[6];
    const float* var       = (const float*)d_in[7];
    const float* w_conv    = (const float*)d_in[8];
    const float* b_conv    = (const float*)d_in[9];
    float* out = (float*)d_out;
    float* ws  = (float*)d_ws;

    prep_kernel<<<160, 256, 0, stream>>>(w_squeeze, w_conv, gamma, beta, mean, var, ws);
    squeeze_kernel<<<(B * H * W) / 64, 256, 0, stream>>>(x, ws, out);
    fused_kernel<<<B * 8 * 8, 256, 0, stream>>>(ws, w_gw, w_gf, b_conv, out);
}

// Round 2
// 454.787 us; speedup vs baseline: 1.2209x; 1.2209x over previous
//
#include <hip/hip_runtime.h>
#include <math.h>

typedef __attribute__((ext_vector_type(8))) short short8;
typedef __attribute__((ext_vector_type(4))) float f32x4;

#define B 8
#define H 128
#define W 128
#define C2 128
#define UPC 64
#define CIN 66
#define BN_EPS 1e-5f

// ---- ws layout ----
// floats:  [0, 8388608)                      up (fp32)
// ushorts: [16777216, 16777216+32768)        BSQ fragment stream (bf16)
// ushorts: [16810  -> see below]             BF fragment stream (bf16)
// floats:  [8424448, +594) scale, [+594,+1188) shift
#define UP_OFF   ((size_t)0)
#define BSQ_U16  ((size_t)16777216)
#define BSQ_CNT  32768                 /* 8 kc * 8 nt * 64 * 8 */
#define BF_U16   (BSQ_U16 + BSQ_CNT)
#define BF_CNT   38912                 /* 19 ks * 4 nt * 64 * 8 */
#define SC_F     ((size_t)8424448)
#define SH_F     (SC_F + 594)

static __device__ __forceinline__ unsigned short f2bf(float f) {
    unsigned u = __float_as_uint(f);
    u += 0x7fffu + ((u >> 16) & 1u);      // RNE
    return (unsigned short)(u >> 16);
}
static __device__ __forceinline__ unsigned pack2(float lo, float hi) {
    return (unsigned)f2bf(lo) | ((unsigned)f2bf(hi) << 16);
}

// ------------------------------------------------------------------
// prep: BN fold + B-operand fragment streams (bf16, per-lane order)
// ------------------------------------------------------------------
__global__ void prep_kernel(const float* __restrict__ w_squeeze,
                            const float* __restrict__ gamma,
                            const float* __restrict__ beta,
                            const float* __restrict__ mean,
                            const float* __restrict__ var,
                            const float* __restrict__ w_conv,
                            float* __restrict__ ws)
{
    unsigned short* wsu = (unsigned short*)ws;
    int tid = blockIdx.x * blockDim.x + threadIdx.x;
    int nth = gridDim.x * blockDim.x;

    // squeeze B: k = kc*32 + (lane>>4)*8 + j ; n = nt*16 + (lane&15)
    for (int idx = tid; idx < BSQ_CNT; idx += nth) {
        int j = idx & 7, lane = (idx >> 3) & 63, r = idx >> 9;
        int nt = r & 7, kc = r >> 3;
        int k = kc * 32 + ((lane >> 4) << 3) + j;
        int n = nt * 16 + (lane & 15);
        wsu[BSQ_U16 + idx] = f2bf(w_squeeze[n * 256 + k]);
    }
    // fused B: K padded 594 -> 608 (19 steps), N = 64
    for (int idx = tid; idx < BF_CNT; idx += nth) {
        int j = idx & 7, lane = (idx >> 3) & 63, r = idx >> 9;
        int nt = r & 3, ks = r >> 2;
        int k = ks * 32 + ((lane >> 4) << 3) + j;
        int n = nt * 16 + (lane & 15);
        float v = (k < 594) ? w_conv[n * 594 + k] : 0.f;
        wsu[BF_U16 + idx] = f2bf(v);
    }
    // BN fold
    for (int i = tid; i < CIN * 9; i += nth) {
        float sc = gamma[i] / sqrtf(var[i] + BN_EPS);
        ws[SC_F + i] = sc;
        ws[SH_F + i] = beta[i] - mean[i] * sc;
    }
}

// ------------------------------------------------------------------
// squeeze: space-to-depth + 1x1 conv as bf16 MFMA GEMM
//   block: 256 thr, 64 consecutive-w pixels, K=256, N=128
// ------------------------------------------------------------------
__global__ __launch_bounds__(256) void squeeze_mfma(
    const float* __restrict__ x,
    float* __restrict__ wsp,
    float* __restrict__ out)
{
    __shared__ uint4 As[32 * 66];   // [kb][pix], pad 66

    const int m0 = blockIdx.x * 64;
    const int w0 = m0 & 127;
    const int h  = (m0 >> 7) & 127;
    const int b  = m0 >> 14;
    const int tid  = threadIdx.x;
    const int lane = tid & 63;      // pixel during fill
    const int wv   = tid >> 6;

    // ---- fill A (bf16, fragment row layout) ----
#pragma unroll
    for (int it = 0; it < 4; ++it) {
        const int t = wv * 4 + it;          // 16 classes (gy, oct)
        const int gy = t & 1, oct = t >> 1;
        const size_t base = ((size_t)(b * 64 + oct * 8) * 256 + (2 * h + gy)) * 256
                          + 2 * (w0 + lane);
        float2 v[8];
#pragma unroll
        for (int i = 0; i < 8; ++i)
            v[i] = *(const float2*)(x + base + (size_t)i * 65536);
        uint4 lo, hi;
        lo.x = pack2(v[0].x, v[1].x); lo.y = pack2(v[2].x, v[3].x);
        lo.z = pack2(v[4].x, v[5].x); lo.w = pack2(v[6].x, v[7].x);
        hi.x = pack2(v[0].y, v[1].y); hi.y = pack2(v[2].y, v[3].y);
        hi.z = pack2(v[4].y, v[5].y); hi.w = pack2(v[6].y, v[7].y);
        As[(gy * 8 + oct) * 66 + lane]       = lo;   // g = gy      (gx=0)
        As[((gy + 2) * 8 + oct) * 66 + lane] = hi;   // g = gy + 2  (gx=1)
    }
    __syncthreads();

    // ---- MFMA ----
    const unsigned short* bsq = (const unsigned short*)wsp + BSQ_U16;
    const int q = lane >> 4, m = lane & 15;
    f32x4 acc[8];
#pragma unroll
    for (int nt = 0; nt < 8; ++nt) acc[nt] = (f32x4){0.f, 0.f, 0.f, 0.f};

#pragma unroll
    for (int ks = 0; ks < 8; ++ks) {
        short8 a = *(const short8*)&As[(ks * 4 + q) * 66 + wv * 16 + m];
#pragma unroll
        for (int nt = 0; nt < 8; ++nt) {
            short8 bb = *(const short8*)(bsq + (size_t)((ks * 8 + nt) * 64 + lane) * 8);
            acc[nt] = __builtin_amdgcn_mfma_f32_16x16x32_bf16(a, bb, acc[nt], 0, 0, 0);
        }
    }

    // ---- epilogue: up -> ws (fp32), low -> out (permuted) ----
#pragma unroll
    for (int nt = 0; nt < 8; ++nt) {
        const int oc = nt * 16 + m;
#pragma unroll
        for (int r = 0; r < 4; ++r) {
            const int pix = wv * 16 + q * 4 + r;
            const int wc  = w0 + pix;
            const float vv = acc[nt][r];
            if (oc < UPC) {
                wsp[UP_OFF + ((size_t)((b * 64 + oc) * 128 + h)) * 128 + wc] = vv;
            } else {
                const int lc = oc - 64;
                const int ch = (lc & 1) ? (96 + ((lc - 1) >> 1)) : (32 + (lc >> 1));
                out[((size_t)((b * 128 + ch) * 128 + h)) * 128 + wc] = vv;
            }
        }
    }
}

// ------------------------------------------------------------------
// fused: softmax-weight + feat conv + BN/ReLU on VALU -> fs (bf16 A),
//        594x64 matvec on MFMA
// ------------------------------------------------------------------
__device__ __forceinline__ void compute_fs(
    int c, const float* __restrict__ trow, int py, int px,
    const float* __restrict__ w_gw, const float* __restrict__ w_gf,
    const float* __restrict__ scp, const float* __restrict__ shp,
    float* __restrict__ fs)
{
    float n[9];
#pragma unroll
    for (int dy = 0; dy < 3; ++dy)
#pragma unroll
        for (int dx = 0; dx < 3; ++dx)
            n[dy * 3 + dx] = trow[(py + dy) * 12 + (px + dx)];
    const float p = (n[0] + n[1] + n[2] + n[3] + n[4] + n[5] + n[6] + n[7] + n[8]) * (1.f / 9.f);

    const float* gw = w_gw + c * 9;
    float lo[9], mx = -INFINITY;
#pragma unroll
    for (int j = 0; j < 9; ++j) { lo[j] = p * gw[j]; mx = fmaxf(mx, lo[j]); }
    float e[9], se = 0.f;
#pragma unroll
    for (int j = 0; j < 9; ++j) { e[j] = __expf(lo[j] - mx); se += e[j]; }
    const float sinv = 1.f / se;

    const float* gf = w_gf + c * 81;
    const float* sc = scp + c * 9;
    const float* sh = shp + c * 9;
#pragma unroll
    for (int j = 0; j < 9; ++j) {
        float cv = n[0] * gf[j * 9 + 0];
        cv = fmaf(n[1], gf[j * 9 + 1], cv); cv = fmaf(n[2], gf[j * 9 + 2], cv);
        cv = fmaf(n[3], gf[j * 9 + 3], cv); cv = fmaf(n[4], gf[j * 9 + 4], cv);
        cv = fmaf(n[5], gf[j * 9 + 5], cv); cv = fmaf(n[6], gf[j * 9 + 6], cv);
        cv = fmaf(n[7], gf[j * 9 + 7], cv); cv = fmaf(n[8], gf[j * 9 + 8], cv);
        float f = fmaf(cv, sc[j], sh[j]);
        f = fmaxf(f, 0.f);
        fs[j] = f * (e[j] * sinv);
    }
}

__global__ __launch_bounds__(256) void fused_mfma(
    const float* __restrict__ wsp,
    const float* __restrict__ w_gw,
    const float* __restrict__ w_gf,
    const float* __restrict__ b_conv,
    float* __restrict__ out)
{
    __shared__ uint4  As[40 * 66];      // 42240 B  [kb][pix]
    __shared__ float  tileS[34 * 120];  // 16320 B  [ci][yy][12]

    const int bx = blockIdx.x;
    const int w0 = (bx & 15) * 8;
    const int h0 = ((bx >> 4) & 15) * 8;
    const int b  = bx >> 8;
    const int tid  = threadIdx.x;
    const int lane = tid & 63;          // = pixel in VALU phase
    const int wv   = tid >> 6;
    const int px = lane & 7, py = lane >> 3;

    const float* upg = wsp + UP_OFF + (size_t)b * UPC * H * W;
    const float* scp = wsp + SC_F;
    const float* shp = wsp + SH_F;
    const unsigned short* bfw = (const unsigned short*)wsp + BF_U16;

    f32x4 acc[4];
#pragma unroll
    for (int nt = 0; nt < 4; ++nt) acc[nt] = (f32x4){0.f, 0.f, 0.f, 0.f};

    const int q = lane >> 4, m = lane & 15;

#pragma unroll 1
    for (int chunk = 0; chunk < 2; ++chunk) {
        const int cs  = chunk ? 32 : 0;
        const int cnt = chunk ? 34 : 32;

        __syncthreads();   // prev MFMA done with As; prev fill done with tile
        // ---- stage tile (8x8 + halo, padded [10][12]) ----
        for (int idx = tid; idx < cnt * 100; idx += 256) {
            int ci = idx / 100, r = idx - ci * 100;
            int yy = r / 10, xx = r - yy * 10;
            int gy = h0 - 1 + yy, gx = w0 - 1 + xx;
            int c = cs + ci;
            float v = 0.f;
            if ((unsigned)gy < 128u && (unsigned)gx < 128u) {
                if (c < 64)       v = upg[((size_t)c * 128 + gy) * 128 + gx];
                else if (c == 64) v = gx * (2.f / 127.f) - 1.f;
                else              v = gy * (2.f / 127.f) - 1.f;
            }
            tileS[ci * 120 + yy * 12 + xx] = v;
        }
        __syncthreads();

        // ---- VALU: fs for 8 channels (72 k = 9 kb, static pack) ----
        {
            const int c0 = cs + 8 * wv;
            float fsa[72];
#pragma unroll
            for (int ci = 0; ci < 8; ++ci)
                compute_fs(c0 + ci, &tileS[(c0 + ci - cs) * 120], py, px,
                           w_gw, w_gf, scp, shp, &fsa[ci * 9]);
            const int kb0 = 9 * wv;
#pragma unroll
            for (int kb = 0; kb < 9; ++kb) {
                uint4 v;
                v.x = pack2(fsa[kb * 8 + 0], fsa[kb * 8 + 1]);
                v.y = pack2(fsa[kb * 8 + 2], fsa[kb * 8 + 3]);
                v.z = pack2(fsa[kb * 8 + 4], fsa[kb * 8 + 5]);
                v.w = pack2(fsa[kb * 8 + 6], fsa[kb * 8 + 7]);
                As[(kb0 + kb) * 66 + lane] = v;
            }
            if (chunk == 1 && wv == 3) {   // c64, c65 + zero pad -> kb 36..39
                float fs2[18];
                compute_fs(64, &tileS[32 * 120], py, px, w_gw, w_gf, scp, shp, &fs2[0]);
                compute_fs(65, &tileS[33 * 120], py, px, w_gw, w_gf, scp, shp, &fs2[9]);
                uint4 v;
                v.x = pack2(fs2[0], fs2[1]);  v.y = pack2(fs2[2], fs2[3]);
                v.z = pack2(fs2[4], fs2[5]);  v.w = pack2(fs2[6], fs2[7]);
                As[36 * 66 + lane] = v;
                v.x = pack2(fs2[8], fs2[9]);  v.y = pack2(fs2[10], fs2[11]);
                v.z = pack2(fs2[12], fs2[13]); v.w = pack2(fs2[14], fs2[15]);
                As[37 * 66 + lane] = v;
                v.x = pack2(fs2[16], fs2[17]); v.y = 0u; v.z = 0u; v.w = 0u;
                As[38 * 66 + lane] = v;
                v.x = 0u; v.y = 0u; v.z = 0u; v.w = 0u;
                As[39 * 66 + lane] = v;
            }
        }
        __syncthreads();

        // ---- MFMA over this K-chunk ----
        const int nsteps = chunk ? 10 : 9;
        const int ksbase = chunk ? 9 : 0;
#pragma unroll 1
        for (int ks = 0; ks < nsteps; ++ks) {
            short8 a = *(const short8*)&As[(ks * 4 + q) * 66 + wv * 16 + m];
#pragma unroll
            for (int nt = 0; nt < 4; ++nt) {
                short8 bb = *(const short8*)(bfw +
                    (size_t)(((ksbase + ks) * 4 + nt) * 64 + lane) * 8);
                acc[nt] = __builtin_amdgcn_mfma_f32_16x16x32_bf16(a, bb, acc[nt], 0, 0, 0);
            }
        }
    }

    // ---- epilogue: bias + channel interleave permute ----
#pragma unroll
    for (int nt = 0; nt < 4; ++nt) {
        const int oc = nt * 16 + m;
        const float bias = b_conv[oc];
        const int ch = (oc & 1) ? (64 + (oc >> 1)) : (oc >> 1);
#pragma unroll
        for (int r = 0; r < 4; ++r) {
            const int pix = wv * 16 + q * 4 + r;
            const int ppy = pix >> 3, ppx = pix & 7;
            out[((size_t)((b * 128 + ch) * 128 + (h0 + ppy))) * 128 + (w0 + ppx)]
                = acc[nt][r] + bias;
        }
    }
}

// ------------------------------------------------------------------
extern "C" void kernel_launch(void* const* d_in, const int* in_sizes, int n_in,
                              void* d_out, int out_size, void* d_ws, size_t ws_size,
                              hipStream_t stream)
{
    const float* x         = (const float*)d_in[0];
    const float* w_squeeze = (const float*)d_in[1];
    const float* w_gw      = (const float*)d_in[2];
    const float* w_gf      = (const float*)d_in[3];
    const float* gamma     = (const float*)d_in[4];
    const float* beta      = (const float*)d_in[5];
    const float* mean      = (const float*)d_in[6];
    const float* var       = (const float*)d_in[7];
    const float* w_conv    = (const float*)d_in[8];
    const float* b_conv    = (const float*)d_in[9];
    float* out = (float*)d_out;
    float* ws  = (float*)d_ws;

    prep_kernel<<<160, 256, 0, stream>>>(w_squeeze, gamma, beta, mean, var, w_conv, ws);
    squeeze_mfma<<<(B * H * W) / 64, 256, 0, stream>>>(x, ws, out);
    fused_mfma<<<B * 16 * 16, 256, 0, stream>>>(ws, w_gw, w_gf, b_conv, out);
}

// Round 3
// 367.206 us; speedup vs baseline: 1.5121x; 1.2385x over previous
//
#include <hip/hip_runtime.h>
#include <math.h>

typedef __attribute__((ext_vector_type(8))) short short8;
typedef __attribute__((ext_vector_type(4))) float f32x4;

#define B 8
#define H 128
#define W 128
#define UPC 64
#define CIN 66
#define BN_EPS 1e-5f

// ---- ws layout ----
#define UP_OFF   ((size_t)0)
#define BSQ_U16  ((size_t)16777216)   /* u16 offset = 32MB */
#define BSQ_CNT  32768                /* 8 kc * 8 nt * 64 * 8 */
#define BF_U16   (BSQ_U16 + BSQ_CNT)
#define BF_CNT   38912                /* 19 ks * 4 nt * 64 * 8 */
#define SC_F     ((size_t)8424448)
#define SH_F     (SC_F + 594)

// precise RNE (prep only — one-time weight conversion)
static __device__ __forceinline__ unsigned short f2bf(float f) {
    unsigned u = __float_as_uint(f);
    u += 0x7fffu + ((u >> 16) & 1u);
    return (unsigned short)(u >> 16);
}
// fast pack: round-half-up + v_perm_b32 (3 VALU instr for 2 values)
static __device__ __forceinline__ unsigned pack2(float lo, float hi) {
    return __builtin_amdgcn_perm(__float_as_uint(hi) + 0x8000u,
                                 __float_as_uint(lo) + 0x8000u, 0x07060302u);
}

// ------------------------------------------------------------------
// prep: BN fold + B-operand fragment streams (bf16, per-lane order)
// ------------------------------------------------------------------
__global__ void prep_kernel(const float* __restrict__ w_squeeze,
                            const float* __restrict__ gamma,
                            const float* __restrict__ beta,
                            const float* __restrict__ mean,
                            const float* __restrict__ var,
                            const float* __restrict__ w_conv,
                            float* __restrict__ ws)
{
    unsigned short* wsu = (unsigned short*)ws;
    int tid = blockIdx.x * blockDim.x + threadIdx.x;
    int nth = gridDim.x * blockDim.x;

    for (int idx = tid; idx < BSQ_CNT; idx += nth) {
        int j = idx & 7, lane = (idx >> 3) & 63, r = idx >> 9;
        int nt = r & 7, kc = r >> 3;
        int k = kc * 32 + ((lane >> 4) << 3) + j;
        int n = nt * 16 + (lane & 15);
        wsu[BSQ_U16 + idx] = f2bf(w_squeeze[n * 256 + k]);
    }
    for (int idx = tid; idx < BF_CNT; idx += nth) {
        int j = idx & 7, lane = (idx >> 3) & 63, r = idx >> 9;
        int nt = r & 3, ks = r >> 2;
        int k = ks * 32 + ((lane >> 4) << 3) + j;
        int n = nt * 16 + (lane & 15);
        float v = (k < 594) ? w_conv[n * 594 + k] : 0.f;
        wsu[BF_U16 + idx] = f2bf(v);
    }
    for (int i = tid; i < CIN * 9; i += nth) {
        float sc = gamma[i] / sqrtf(var[i] + BN_EPS);
        ws[SC_F + i] = sc;
        ws[SH_F + i] = beta[i] - mean[i] * sc;
    }
}

// ------------------------------------------------------------------
// squeeze: space-to-depth + 1x1 conv as bf16 MFMA GEMM
//   wave-split N: wave wv -> nt {2wv, 2wv+1}; B preloaded in registers
// ------------------------------------------------------------------
__global__ __launch_bounds__(256, 3) void squeeze_mfma(
    const float* __restrict__ x,
    float* __restrict__ wsp,
    float* __restrict__ out)
{
    __shared__ uint4 As[32 * 66];   // [kb][pix], pad 66

    const int m0 = blockIdx.x * 64;
    const int w0 = m0 & 127;
    const int h  = (m0 >> 7) & 127;
    const int b  = m0 >> 14;
    const int tid  = threadIdx.x;
    const int lane = tid & 63;
    const int wv   = tid >> 6;

    // ---- B preload: 16 fragments (64 VGPRs), issued before A-fill ----
    const unsigned short* bsq = (const unsigned short*)wsp + BSQ_U16;
    short8 breg[2][8];
#pragma unroll
    for (int ks = 0; ks < 8; ++ks)
#pragma unroll
        for (int j = 0; j < 2; ++j)
            breg[j][ks] = *(const short8*)(bsq +
                (size_t)((ks * 8 + (2 * wv + j)) * 64 + lane) * 8);

    // ---- fill A (bf16, fragment row layout) ----
#pragma unroll 2
    for (int it = 0; it < 4; ++it) {
        const int t = wv * 4 + it;          // 16 classes (gy, oct)
        const int gy = t & 1, oct = t >> 1;
        const size_t base = ((size_t)(b * 64 + oct * 8) * 256 + (2 * h + gy)) * 256
                          + 2 * (w0 + lane);
        float2 v[8];
#pragma unroll
        for (int i = 0; i < 8; ++i)
            v[i] = *(const float2*)(x + base + (size_t)i * 65536);
        uint4 lo, hi;
        lo.x = pack2(v[0].x, v[1].x); lo.y = pack2(v[2].x, v[3].x);
        lo.z = pack2(v[4].x, v[5].x); lo.w = pack2(v[6].x, v[7].x);
        hi.x = pack2(v[0].y, v[1].y); hi.y = pack2(v[2].y, v[3].y);
        hi.z = pack2(v[4].y, v[5].y); hi.w = pack2(v[6].y, v[7].y);
        As[(gy * 8 + oct) * 66 + lane]       = lo;   // g = gy      (gx=0)
        As[((gy + 2) * 8 + oct) * 66 + lane] = hi;   // g = gy + 2  (gx=1)
    }
    __syncthreads();

    // ---- MFMA: M=64 (4 mt) x N=32 (2 nt) per wave, zero in-loop loads ----
    const int q = lane >> 4, m = lane & 15;
    f32x4 acc[4][2];
#pragma unroll
    for (int mt = 0; mt < 4; ++mt)
#pragma unroll
        for (int j = 0; j < 2; ++j) acc[mt][j] = (f32x4){0.f, 0.f, 0.f, 0.f};

#pragma unroll
    for (int ks = 0; ks < 8; ++ks)
#pragma unroll
        for (int mt = 0; mt < 4; ++mt) {
            short8 a = *(const short8*)&As[(ks * 4 + q) * 66 + mt * 16 + m];
            acc[mt][0] = __builtin_amdgcn_mfma_f32_16x16x32_bf16(a, breg[0][ks], acc[mt][0], 0, 0, 0);
            acc[mt][1] = __builtin_amdgcn_mfma_f32_16x16x32_bf16(a, breg[1][ks], acc[mt][1], 0, 0, 0);
        }

    // ---- epilogue (oc range uniform per wave: wv<2 -> up, wv>=2 -> low) ----
#pragma unroll
    for (int j = 0; j < 2; ++j) {
        const int oc = (2 * wv + j) * 16 + m;
#pragma unroll
        for (int mt = 0; mt < 4; ++mt)
#pragma unroll
            for (int r = 0; r < 4; ++r) {
                const int wc = w0 + mt * 16 + q * 4 + r;
                const float vv = acc[mt][j][r];
                if (oc < UPC) {
                    wsp[UP_OFF + ((size_t)((b * 64 + oc) * 128 + h)) * 128 + wc] = vv;
                } else {
                    const int lc = oc - 64;
                    const int ch = (lc & 1) ? (96 + ((lc - 1) >> 1)) : (32 + (lc >> 1));
                    out[((size_t)((b * 128 + ch) * 128 + h)) * 128 + wc] = vv;
                }
            }
    }
}

// ------------------------------------------------------------------
// fused kernel helpers
// ------------------------------------------------------------------
__device__ __forceinline__ void fs_from_n(
    int cu, const float n[9],
    const float* __restrict__ w_gw, const float* __restrict__ w_gf,
    const float* __restrict__ scp, const float* __restrict__ shp,
    float fs[9])
{
    const float p = (n[0] + n[1] + n[2] + n[3] + n[4] + n[5] + n[6] + n[7] + n[8]) * (1.f / 9.f);
    const float* gw = w_gw + cu * 9;
    const float* gf = w_gf + cu * 81;
    const float* sc = scp + cu * 9;
    const float* sh = shp + cu * 9;
    float e[9], se = 0.f;
#pragma unroll
    for (int j = 0; j < 9; ++j) { e[j] = __expf(p * gw[j]); se += e[j]; }
    const float sinv = 1.f / se;
#pragma unroll
    for (int j = 0; j < 9; ++j) {
        float cv = n[0] * gf[j * 9 + 0];
        cv = fmaf(n[1], gf[j * 9 + 1], cv); cv = fmaf(n[2], gf[j * 9 + 2], cv);
        cv = fmaf(n[3], gf[j * 9 + 3], cv); cv = fmaf(n[4], gf[j * 9 + 4], cv);
        cv = fmaf(n[5], gf[j * 9 + 5], cv); cv = fmaf(n[6], gf[j * 9 + 6], cv);
        cv = fmaf(n[7], gf[j * 9 + 7], cv); cv = fmaf(n[8], gf[j * 9 + 8], cv);
        float f = fmaf(cv, sc[j], sh[j]);
        fs[j] = fmaxf(f, 0.f) * (e[j] * sinv);
    }
}

__device__ __forceinline__ void pack_into(unsigned* pk, int ci, const float fs[9], float& carry)
{
    const int off = 9 * ci;
    if ((ci & 1) == 0) {
#pragma unroll
        for (int t = 0; t < 4; ++t) pk[off / 2 + t] = pack2(fs[2 * t], fs[2 * t + 1]);
        carry = fs[8];
    } else {
        pk[(off - 1) / 2] = pack2(carry, fs[0]);
#pragma unroll
        for (int t = 0; t < 4; ++t) pk[(off + 1) / 2 + t] = pack2(fs[1 + 2 * t], fs[2 + 2 * t]);
    }
}

template<bool BORDER>
__device__ __forceinline__ void chunk_fs(
    int cs, int wv, int lane, int h0, int w0,
    const float* __restrict__ upg,
    const float* __restrict__ w_gw, const float* __restrict__ w_gf,
    const float* __restrict__ scp, const float* __restrict__ shp,
    unsigned pk[36])
{
    const int px = lane & 7, py = lane >> 3;
    const int gy0 = h0 + py - 1, gx0 = w0 + px - 1;
    float carry = 0.f;
#pragma unroll
    for (int ci = 0; ci < 8; ++ci) {
        const int cu = __builtin_amdgcn_readfirstlane(cs + 8 * wv + ci);
        const float* cb = upg + (size_t)cu * (H * W) + gy0 * W + gx0;
        float n[9];
        if (!BORDER) {
#pragma unroll
            for (int dy = 0; dy < 3; ++dy)
#pragma unroll
                for (int dx = 0; dx < 3; ++dx)
                    n[dy * 3 + dx] = cb[dy * W + dx];
        } else {
#pragma unroll
            for (int dy = 0; dy < 3; ++dy)
#pragma unroll
                for (int dx = 0; dx < 3; ++dx) {
                    const int gy = gy0 + dy, gx = gx0 + dx;
                    const bool ok = ((unsigned)gy < 128u) & ((unsigned)gx < 128u);
                    n[dy * 3 + dx] = ok ? cb[dy * W + dx] : 0.f;
                }
        }
        float fs[9];
        fs_from_n(cu, n, w_gw, w_gf, scp, shp, fs);
        pack_into(pk, ci, fs, carry);
    }
}

__device__ __forceinline__ void coord_n(int which, int h0, int w0, int lane, float n[9])
{
    const int px = lane & 7, py = lane >> 3;
#pragma unroll
    for (int dy = 0; dy < 3; ++dy)
#pragma unroll
        for (int dx = 0; dx < 3; ++dx) {
            const int gy = h0 + py - 1 + dy, gx = w0 + px - 1 + dx;
            const bool ok = ((unsigned)gy < 128u) & ((unsigned)gx < 128u);
            const float v = (which == 0) ? (gx * (2.f / 127.f) - 1.f)
                                         : (gy * (2.f / 127.f) - 1.f);
            n[dy * 3 + dx] = ok ? v : 0.f;
        }
}

template<int NSTEPS>
__device__ __forceinline__ void do_mfma(
    int base, const uint4* As, const unsigned short* __restrict__ bfw,
    int wv, int lane, f32x4 acc[2][2])
{
    const int q = lane >> 4, m = lane & 15;
    const int ntb = (wv >> 1) * 2;
    const int pt0 = (wv & 1) * 2;
#pragma unroll
    for (int ks = 0; ks < NSTEPS; ++ks) {
        short8 b0 = *(const short8*)(bfw + (size_t)(((base + ks) * 4 + ntb + 0) * 64 + lane) * 8);
        short8 b1 = *(const short8*)(bfw + (size_t)(((base + ks) * 4 + ntb + 1) * 64 + lane) * 8);
#pragma unroll
        for (int mt = 0; mt < 2; ++mt) {
            short8 a = *(const short8*)&As[(ks * 4 + q) * 64 + (pt0 + mt) * 16 + m];
            acc[mt][0] = __builtin_amdgcn_mfma_f32_16x16x32_bf16(a, b0, acc[mt][0], 0, 0, 0);
            acc[mt][1] = __builtin_amdgcn_mfma_f32_16x16x32_bf16(a, b1, acc[mt][1], 0, 0, 0);
        }
    }
}

// ------------------------------------------------------------------
// fused: fs on VALU (direct global neighborhood reads), matvec on MFMA
//   LDS = 40960 B exactly -> 4 blocks/CU; launch_bounds caps VGPR at 128
// ------------------------------------------------------------------
__global__ __launch_bounds__(256, 4) void fused_mfma(
    const float* __restrict__ wsp,
    const float* __restrict__ w_gw,
    const float* __restrict__ w_gf,
    const float* __restrict__ b_conv,
    float* __restrict__ out)
{
    __shared__ uint4 As[40 * 64];   // 40960 B

    const int bx = blockIdx.x;
    const int w0 = (bx & 15) * 8;
    const int h0 = ((bx >> 4) & 15) * 8;
    const int b  = bx >> 8;
    const int tid = threadIdx.x, lane = tid & 63, wv = tid >> 6;
    const bool interior = (h0 > 0) & (h0 < 120) & (w0 > 0) & (w0 < 120);

    const float* upg = wsp + UP_OFF + (size_t)b * UPC * H * W;
    const float* scp = wsp + SC_F;
    const float* shp = wsp + SH_F;
    const unsigned short* bfw = (const unsigned short*)wsp + BF_U16;

    f32x4 acc[2][2];
#pragma unroll
    for (int mt = 0; mt < 2; ++mt)
#pragma unroll
        for (int j = 0; j < 2; ++j) acc[mt][j] = (f32x4){0.f, 0.f, 0.f, 0.f};

    // ================= chunk 0 : channels 0..31 =================
    {
        unsigned pk[36];
        if (interior) chunk_fs<false>(0, wv, lane, h0, w0, upg, w_gw, w_gf, scp, shp, pk);
        else          chunk_fs<true >(0, wv, lane, h0, w0, upg, w_gw, w_gf, scp, shp, pk);
        __syncthreads();
#pragma unroll
        for (int kb = 0; kb < 9; ++kb)
            As[(9 * wv + kb) * 64 + lane] =
                (uint4){pk[4 * kb], pk[4 * kb + 1], pk[4 * kb + 2], pk[4 * kb + 3]};
        __syncthreads();
        do_mfma<9>(0, As, bfw, wv, lane, acc);
    }

    // ================= chunk 1 : channels 32..65 + pad =================
    {
        unsigned pk[36];
        if (interior) chunk_fs<false>(32, wv, lane, h0, w0, upg, w_gw, w_gf, scp, shp, pk);
        else          chunk_fs<true >(32, wv, lane, h0, w0, upg, w_gw, w_gf, scp, shp, pk);

        float fsA[9], fsB[9];
        if (wv == 3) {   // coordinate channels 64, 65
            float n2[9];
            coord_n(0, h0, w0, lane, n2);
            fs_from_n(64, n2, w_gw, w_gf, scp, shp, fsA);
            coord_n(1, h0, w0, lane, n2);
            fs_from_n(65, n2, w_gw, w_gf, scp, shp, fsB);
        }
        __syncthreads();   // all waves done reading As (chunk0 MFMA)
#pragma unroll
        for (int kb = 0; kb < 9; ++kb)
            As[(9 * wv + kb) * 64 + lane] =
                (uint4){pk[4 * kb], pk[4 * kb + 1], pk[4 * kb + 2], pk[4 * kb + 3]};
        if (wv == 3) {
            uint4 v;
            v.x = pack2(fsA[0], fsA[1]); v.y = pack2(fsA[2], fsA[3]);
            v.z = pack2(fsA[4], fsA[5]); v.w = pack2(fsA[6], fsA[7]);
            As[36 * 64 + lane] = v;
            v.x = pack2(fsA[8], fsB[0]); v.y = pack2(fsB[1], fsB[2]);
            v.z = pack2(fsB[3], fsB[4]); v.w = pack2(fsB[5], fsB[6]);
            As[37 * 64 + lane] = v;
            v.x = pack2(fsB[7], fsB[8]); v.y = 0u; v.z = 0u; v.w = 0u;
            As[38 * 64 + lane] = v;
            v.x = 0u; v.y = 0u; v.z = 0u; v.w = 0u;
            As[39 * 64 + lane] = v;
        }
        __syncthreads();
        do_mfma<10>(9, As, bfw, wv, lane, acc);
    }

    // ================= epilogue =================
    const int q = lane >> 4, m = lane & 15;
    const int ntb = (wv >> 1) * 2, pt0 = (wv & 1) * 2;
#pragma unroll
    for (int mt = 0; mt < 2; ++mt)
#pragma unroll
        for (int j = 0; j < 2; ++j) {
            const int oc = (ntb + j) * 16 + m;
            const float bias = b_conv[oc];
            const int ch = (oc & 1) ? (64 + (oc >> 1)) : (oc >> 1);
#pragma unroll
            for (int r = 0; r < 4; ++r) {
                const int pix = (pt0 + mt) * 16 + q * 4 + r;
                out[((size_t)((b * 128 + ch) * 128 + (h0 + (pix >> 3)))) * 128
                    + (w0 + (pix & 7))] = acc[mt][j][r] + bias;
            }
        }
}

// ------------------------------------------------------------------
extern "C" void kernel_launch(void* const* d_in, const int* in_sizes, int n_in,
                              void* d_out, int out_size, void* d_ws, size_t ws_size,
                              hipStream_t stream)
{
    const float* x         = (const float*)d_in[0];
    const float* w_squeeze = (const float*)d_in[1];
    const float* w_gw      = (const float*)d_in[2];
    const float* w_gf      = (const float*)d_in[3];
    const float* gamma     = (const float*)d_in[4];
    const float* beta      = (const float*)d_in[5];
    const float* mean      = (const float*)d_in[6];
    const float* var       = (const float*)d_in[7];
    const float* w_conv    = (const float*)d_in[8];
    const float* b_conv    = (const float*)d_in[9];
    float* out = (float*)d_out;
    float* ws  = (float*)d_ws;

    prep_kernel<<<160, 256, 0, stream>>>(w_squeeze, gamma, beta, mean, var, w_conv, ws);
    squeeze_mfma<<<(B * H * W) / 64, 256, 0, stream>>>(x, ws, out);
    fused_mfma<<<B * 16 * 16, 256, 0, stream>>>(ws, w_gw, w_gf, b_conv, out);
}